// Round 5
// baseline (524.190 us; speedup 1.0000x reference)
//
#include <hip/hip_runtime.h>
#include <cstdint>

// ---------- problem constants ----------
#define B_   2
#define S_   4096
#define D_   768
#define H_   12
#define DH_  64
#define BH_  (B_*H_)       // 24
#define M_   (B_*S_)       // 8192
#define SCALE 0.125f       // 1/sqrt(64)

typedef _Float16 fp16;
typedef __attribute__((ext_vector_type(8))) _Float16 fp16x8;
typedef __attribute__((ext_vector_type(4))) _Float16 fp16x4;
typedef __attribute__((ext_vector_type(4))) float    f32x4;

#define MFMA16(a,b,c) __builtin_amdgcn_mfma_f32_16x16x32_f16((a),(b),(c),0,0,0)

// ---------- async global->LDS, 16B ----------
__device__ __forceinline__ void gld_lds16(const void* g, void* l) {
  __builtin_amdgcn_global_load_lds(
      (const __attribute__((address_space(1))) unsigned int*)g,
      (__attribute__((address_space(3))) unsigned int*)l, 16, 0, 0);
}

// Stage a 64-row x 128-byte tile into LDS. Linear LDS dest (required by
// global_load_lds), inverse-swizzled GLOBAL source, swizzled reads (m173/m201
// pattern).  Linear offset o holds global element (row=o>>7,
// colbyte=(o&127)^((row&7)<<4)).
__device__ __forceinline__ void stage64x128(const char* gbase, int pitch,
                                            char* lds, int tid) {
  const int lane = tid & 63, wv = tid >> 6;
#pragma unroll
  for (int j = 0; j < 2; ++j) {
    const int o   = (wv*2 + j)*1024 + lane*16;
    const int row = o >> 7;
    const int cb  = (o & 127) ^ ((row & 7) << 4);
    gld_lds16(gbase + (size_t)row*pitch + cb, lds + (wv*2 + j)*1024);
  }
}

// swizzled 16B LDS read (8 halves) from a 64x128B tile
__device__ __forceinline__ fp16x8 lds_h8(const char* base, int row, int cb) {
  return *(const fp16x8*)(base + row*128 + (cb ^ ((row & 7) << 4)));
}

// ---------- kernel 1: W transpose + hi/lo split ----------
// wt layout: per matrix {hi plane [n][k], lo plane [n][k]}, 768x768 f16 each
__global__ __launch_bounds__(256) void prep_w(const float* __restrict__ wq,
                                              const float* __restrict__ wk,
                                              const float* __restrict__ wv,
                                              fp16* __restrict__ wt) {
  const int idx = blockIdx.x*256 + threadIdx.x;       // 3*768*768 total
  const int mat = idx / (768*768);
  const int e   = idx % (768*768);
  const int n   = e / 768, k = e % 768;
  const float* w = mat == 0 ? wq : (mat == 1 ? wk : wv);
  const float v = w[(size_t)k*768 + n];
  fp16* base = wt + (size_t)mat * (2*768*768);
  const fp16 hv = (fp16)v;
  base[e]            = hv;                 // hi
  base[768*768 + e]  = (fp16)(v - (float)hv);  // lo
}

// ---------- kernel 2: projection GEMM (f16x3), 64x64 tile ----------
// mat 0/1 -> hi+lo planes [BH][S][64]; mat 2 -> single f16 transposed [BH][64][S]
__global__ __launch_bounds__(256) void proj_gemm(
    const float* __restrict__ xq, const float* __restrict__ xk,
    const float* __restrict__ xv, const fp16* __restrict__ wt,
    fp16* __restrict__ qhi, fp16* __restrict__ qlo,
    fp16* __restrict__ khi, fp16* __restrict__ klo,
    fp16* __restrict__ vtp) {
  __shared__ __align__(16) char sm[16384];
  char* sWh = sm;
  char* sWl = sm + 8192;
  const int tid = threadIdx.x, lane = tid & 63, wv = tid >> 6;
  const int c = lane & 15, g = lane >> 4;
  const int mb  = blockIdx.x * 64;
  const int h   = blockIdx.y;        // one 64-wide n-tile == one head
  const int nb  = h * 64;
  const int mat = blockIdx.z;
  const float* x = mat == 0 ? xq : (mat == 1 ? xk : xv);
  const fp16* wth = wt + (size_t)mat * (2*768*768);
  const fp16* wtl = wth + 768*768;

  f32x4 acc[4] = {};
  const int xrow = mb + wv*16 + c;   // A-fragment row (= l&15)

  for (int k0 = 0; k0 < 768; k0 += 64) {
    __syncthreads();
    stage64x128((const char*)(wth + (size_t)nb*768 + k0), 768*2, sWh, tid);
    stage64x128((const char*)(wtl + (size_t)nb*768 + k0), 768*2, sWl, tid);
    __syncthreads();

    fp16x8 ah[2], al[2];
#pragma unroll
    for (int ks = 0; ks < 2; ++ks) {
      const float* xp = x + (size_t)xrow*768 + k0 + ks*32 + g*8;
      const f32x4 x0 = *(const f32x4*)xp;
      const f32x4 x1 = *(const f32x4*)(xp + 4);
#pragma unroll
      for (int j = 0; j < 8; ++j) {
        const float v = j < 4 ? x0[j] : x1[j - 4];
        const fp16 hv = (fp16)v;
        ah[ks][j] = hv;
        al[ks][j] = (fp16)(v - (float)hv);
      }
    }
#pragma unroll
    for (int ks = 0; ks < 2; ++ks)
#pragma unroll
      for (int nt = 0; nt < 4; ++nt) {
        const fp16x8 bh = lds_h8(sWh, nt*16 + c, ks*64 + g*16);
        const fp16x8 bl = lds_h8(sWl, nt*16 + c, ks*64 + g*16);
        acc[nt] = MFMA16(ah[ks], bh, acc[nt]);   // hi*hi
        acc[nt] = MFMA16(ah[ks], bl, acc[nt]);   // hi*lo
        acc[nt] = MFMA16(al[ks], bh, acc[nt]);   // lo*hi
      }
  }

  if (mat < 2) {
    fp16* ph = mat ? khi : qhi;
    fp16* pl = mat ? klo : qlo;
#pragma unroll
    for (int nt = 0; nt < 4; ++nt)
#pragma unroll
      for (int r = 0; r < 4; ++r) {
        const int m = mb + wv*16 + g*4 + r;      // C/D row = 4*(l>>4)+reg
        const int bb = m >> 12, s = m & (S_-1);
        const size_t idx = ((size_t)(bb*H_ + h)*S_ + s)*DH_ + nt*16 + c;
        const float v = acc[nt][r];
        const fp16 hv = (fp16)v;
        ph[idx] = hv;
        pl[idx] = (fp16)(v - (float)hv);
      }
  } else {
    // V: transpose 64x64 tile through LDS, store [d][s] coalesced
    __syncthreads();
    fp16* tile = (fp16*)sm;   // [64 d][64 m_local]
#pragma unroll
    for (int nt = 0; nt < 4; ++nt) {
      const int dd = nt*16 + c, ml = wv*16 + g*4;
      const fp16x4 hv = {(fp16)acc[nt][0], (fp16)acc[nt][1],
                         (fp16)acc[nt][2], (fp16)acc[nt][3]};
      *(fp16x4*)(tile + dd*64 + ml) = hv;
    }
    __syncthreads();
    const int bb = mb >> 12, s0 = mb & (S_-1);
    const int dd = tid >> 2, ml0 = (tid & 3) * 16;
    const size_t obase = ((size_t)(bb*H_ + h)*DH_ + dd)*S_ + s0 + ml0;
#pragma unroll
    for (int u = 0; u < 2; ++u)
      *(fp16x8*)(vtp + obase + u*8) = *(const fp16x8*)(tile + dd*64 + ml0 + u*8);
  }
}

// ---------- kernel 3: flash attention ----------
// WG = one (b,h) x 64 q-rows; 4 waves x 16-q strips; kt loop over 64-kv tiles.
// Swapped QK^T: D[kv][q] = mfma(A=K_frag, B=Qt_frag)  -> lane column = one q.
__global__ __launch_bounds__(256) void mha_flash(
    const fp16* __restrict__ qhi, const fp16* __restrict__ qlo,
    const fp16* __restrict__ khi, const fp16* __restrict__ klo,
    const fp16* __restrict__ vt, float* __restrict__ out) {
  __shared__ __align__(16) char sm[49152];
  char* sQh = sm;             // 8KB each
  char* sQl = sm + 8192;
  char* sKh = sm + 16384;
  char* sKl = sm + 24576;
  char* sV  = sm + 32768;
  char* sP  = sm + 40960;     // 4 waves x 2KB

  const int tid = threadIdx.x, lane = tid & 63, wv = tid >> 6;
  const int c = lane & 15, g = lane >> 4;
  const int qb = blockIdx.x * 64;
  const int bh = blockIdx.y;
  const int b = bh / H_, h = bh % H_;

  const size_t qoff = ((size_t)bh*S_ + qb) * DH_;
  stage64x128((const char*)(qhi + qoff), 128, sQh, tid);
  stage64x128((const char*)(qlo + qoff), 128, sQl, tid);
  __syncthreads();

  fp16x8 qfh[2], qfl[2];      // Qt B-fragments for this wave's 16-q strip
#pragma unroll
  for (int ks = 0; ks < 2; ++ks) {
    qfh[ks] = lds_h8(sQh, wv*16 + c, ks*64 + g*16);
    qfl[ks] = lds_h8(sQl, wv*16 + c, ks*64 + g*16);
  }

  float m_run = -1e30f, l_run = 0.f;
  f32x4 accO[4] = {};

  for (int kt = 0; kt < S_/64; ++kt) {
    const int kvb = kt * 64;
    __syncthreads();
    const size_t koff = ((size_t)bh*S_ + kvb) * DH_;
    stage64x128((const char*)(khi + koff), 128, sKh, tid);
    stage64x128((const char*)(klo + koff), 128, sKl, tid);
    stage64x128((const char*)(vt + (size_t)bh*DH_*S_ + kvb), S_*2, sV, tid);
    __syncthreads();

    // QK^T, f16x3
    f32x4 accS[4] = {};
#pragma unroll
    for (int t = 0; t < 4; ++t)
#pragma unroll
      for (int ks = 0; ks < 2; ++ks) {
        const fp16x8 kfh = lds_h8(sKh, t*16 + c, ks*64 + g*16);
        const fp16x8 kfl = lds_h8(sKl, t*16 + c, ks*64 + g*16);
        accS[t] = MFMA16(kfh, qfh[ks], accS[t]);
        accS[t] = MFMA16(kfh, qfl[ks], accS[t]);
        accS[t] = MFMA16(kfl, qfh[ks], accS[t]);
      }

    // online softmax: lane holds 16 of 64 kv scores for q=c; reduce over g
    float mx = -1e30f;
#pragma unroll
    for (int t = 0; t < 4; ++t)
#pragma unroll
      for (int r = 0; r < 4; ++r) mx = fmaxf(mx, accS[t][r]);
    mx = fmaxf(mx, __shfl_xor(mx, 16));
    mx = fmaxf(mx, __shfl_xor(mx, 32));
    const float m_new = fmaxf(m_run, mx);
    const float corr = __expf((m_run - m_new) * SCALE);
    float psum = 0.f;
#pragma unroll
    for (int t = 0; t < 4; ++t)
#pragma unroll
      for (int r = 0; r < 4; ++r) {
        const float p = __expf((accS[t][r] - m_new) * SCALE);
        accS[t][r] = p;
        psum += p;
      }
    psum += __shfl_xor(psum, 16);
    psum += __shfl_xor(psum, 32);
    l_run = l_run * corr + psum;
    m_run = m_new;

    // P -> this wave's LDS strip, [16 q][64 kv] f16, swizzled; regs are
    // consecutive kv (kv = t*16 + 4g + r) -> pack 4 and ds_write_b64
    char* pbase = sP + wv*2048;
#pragma unroll
    for (int t = 0; t < 4; ++t) {
      const fp16x4 pw = {(fp16)accS[t][0], (fp16)accS[t][1],
                         (fp16)accS[t][2], (fp16)accS[t][3]};
      *(fp16x4*)(pbase + c*128 + ((t*32 + g*8) ^ ((c & 7) << 4))) = pw;
    }

    // rescale O: accO rows are q'=4g+r, but corr is per q=c -> shuffle
    float cr[4];
#pragma unroll
    for (int r = 0; r < 4; ++r)
      cr[r] = __shfl(corr, (lane & 48) | (g*4 + r));
#pragma unroll
    for (int d = 0; d < 4; ++d)
#pragma unroll
      for (int r = 0; r < 4; ++r) accO[d][r] *= cr[r];

    // PV: A = P (rows q), B = V^T tile (k-contiguous reads)
#pragma unroll
    for (int ks = 0; ks < 2; ++ks) {
      const fp16x8 pf = *(const fp16x8*)(pbase + c*128 +
                                         ((ks*64 + g*16) ^ ((c & 7) << 4)));
#pragma unroll
      for (int d = 0; d < 4; ++d) {
        const fp16x8 vf = lds_h8(sV, d*16 + c, ks*64 + g*16);
        accO[d] = MFMA16(pf, vf, accO[d]);
      }
    }
  }

  float inv[4];
#pragma unroll
  for (int r = 0; r < 4; ++r)
    inv[r] = 1.f / __shfl(l_run, (lane & 48) | (g*4 + r));
  const int s0 = qb + wv*16 + g*4;
#pragma unroll
  for (int d = 0; d < 4; ++d)
#pragma unroll
    for (int r = 0; r < 4; ++r)
      out[((size_t)(b*S_ + s0 + r))*D_ + h*DH_ + d*16 + c] = accO[d][r] * inv[r];
}

// ---------- launch ----------
extern "C" void kernel_launch(void* const* d_in, const int* in_sizes, int n_in,
                              void* d_out, int out_size, void* d_ws, size_t ws_size,
                              hipStream_t stream) {
  const float* xq = (const float*)d_in[0];
  const float* xk = (const float*)d_in[1];
  const float* xv = (const float*)d_in[2];
  const float* wq = (const float*)d_in[3];
  const float* wk = (const float*)d_in[4];
  const float* wv = (const float*)d_in[5];
  float* out = (float*)d_out;

  // workspace layout (f16): Wt planes (6x768x768) | Qhi | Qlo | Khi | Klo | Vt
  // total ~70.0 MB
  fp16* wt  = (fp16*)d_ws;
  fp16* qhi = wt + (size_t)6*768*768;
  const size_t PL = (size_t)BH_*S_*DH_;    // 6.29M halves per plane
  fp16* qlo = qhi + PL;
  fp16* khi = qlo + PL;
  fp16* klo = khi + PL;
  fp16* vtp = klo + PL;

  hipLaunchKernelGGL(prep_w, dim3(3*768*768/256), dim3(256), 0, stream,
                     wq, wk, wv, wt);
  hipLaunchKernelGGL(proj_gemm, dim3(M_/64, H_, 3), dim3(256), 0, stream,
                     xq, xk, xv, wt, qhi, qlo, khi, klo, vtp);
  hipLaunchKernelGGL(mha_flash, dim3(S_/64, BH_), dim3(256), 0, stream,
                     qhi, qlo, khi, klo, vtp, out);
}